// Round 6
// baseline (274.891 us; speedup 1.0000x reference)
//
#include <hip/hip_runtime.h>
#include <math.h>

// EfficientDet post-processing, device pipeline v6.
// prep(decode+transpose) -> sliced hist(vec4) -> pivot(parallel scan) ->
// sliced collect(vec4) -> sort(hybrid bitonic) -> mask(720 blocks, no atomics)
// -> scan(readlane chain) -> top-100.

#define A_N   110484
#define C_N   90
#define KCAND 512
#define NBINS 8192        // 13-bit histogram bins (key >> 19)
#define KSH   19
#define MAXDET 100
#define IMG_F 768.0f
#define THRESH 0.05f
#define NSLICE 8
#define VTOT   (A_N / 4)                          // 27621 (A_N divisible by 4)
#define VSLICE ((VTOT + NSLICE - 1) / NSLICE)     // 3453
#define CAND_CAP 2048
#define T_BLKS ((A_N + 63) / 64)     // 1727 transpose blocks
#define D_BLKS ((A_N + 255) / 256)   // 432 decode blocks

typedef unsigned int u32;
typedef unsigned long long u64;

__device__ __forceinline__ u32 fkey(float f) {
    u32 u = __float_as_uint(f);
    return (u & 0x80000000u) ? ~u : (u | 0x80000000u);
}
__device__ __forceinline__ float unfkey(u32 k) {
    u32 u = (k & 0x80000000u) ? (k ^ 0x80000000u) : ~k;
    return __uint_as_float(u);
}
__device__ __forceinline__ u64 shflx64(u64 v, int m) {
    u32 lo = (u32)__shfl_xor((int)(u32)v, m, 64);
    u32 hi = (u32)__shfl_xor((int)(v >> 32), m, 64);
    return ((u64)hi << 32) | lo;
}

// ------- Stage 1: fused decode(boxes) + transpose(sigmoid->key) -------
__global__ __launch_bounds__(256)
void prep_kernel(const float* __restrict__ anchors,
                 const float* __restrict__ reg,
                 const float* __restrict__ cls,
                 float4* __restrict__ boxes,
                 u32* __restrict__ keysT) {
    __shared__ u32 tile[64 * 91];   // 23.3 KB, stride 91 (odd) = conflict-free
    if (blockIdx.x >= T_BLKS) {
        int a = (blockIdx.x - T_BLKS) * 256 + threadIdx.x;
        if (a >= A_N) return;
        float4 an = ((const float4*)anchors)[a];
        float4 dl = ((const float4*)reg)[a];
        float wa = an.z - an.x, ha = an.w - an.y;
        float cx = an.x + 0.5f * wa + dl.x * wa;
        float cy = an.y + 0.5f * ha + dl.y * ha;
        float w = expf(dl.z) * wa;
        float h = expf(dl.w) * ha;
        float4 o;
        o.x = fminf(fmaxf(cx - 0.5f * w, 0.0f), IMG_F);
        o.y = fminf(fmaxf(cy - 0.5f * h, 0.0f), IMG_F);
        o.z = fminf(fmaxf(cx + 0.5f * w, 0.0f), IMG_F);
        o.w = fminf(fmaxf(cy + 0.5f * h, 0.0f), IMG_F);
        boxes[a] = o;
        return;
    }
    int a0 = blockIdx.x * 64;
    int lim = min(64, A_N - a0);
    int cnt = lim * C_N;
    const float* src = cls + (size_t)a0 * C_N;
    for (int i = threadIdx.x; i < cnt; i += 256) {
        float x = src[i];
        float s = 1.0f / (1.0f + expf(-x));
        u32 aa = (u32)i / C_N, c = (u32)i % C_N;
        tile[aa * 91 + c] = fkey(s);
    }
    __syncthreads();
    for (int j = threadIdx.x; j < C_N * 64; j += 256) {
        int c = j >> 6, aa = j & 63;
        if (aa < lim)
            keysT[(size_t)c * A_N + a0 + aa] = tile[aa * 91 + c];
    }
}

// ---------------- Stage 2a: sliced per-class histogram (vec4) ----------------
__global__ __launch_bounds__(256)
void hist_kernel(const u32* __restrict__ keysT, u32* __restrict__ ghist) {
    __shared__ u32 h[NBINS];   // 32 KB
    const int c = blockIdx.x / NSLICE, s = blockIdx.x % NSLICE;
    for (int i = threadIdx.x; i < NBINS; i += 256) h[i] = 0;
    __syncthreads();
    const int lo = s * VSLICE, hiEnd = min(VTOT, lo + VSLICE);
    const uint4* kv = (const uint4*)(keysT + (size_t)c * A_N);
    for (int i = lo + threadIdx.x; i < hiEnd; i += 256) {
        uint4 k = kv[i];
        atomicAdd(&h[k.x >> KSH], 1u);
        atomicAdd(&h[k.y >> KSH], 1u);
        atomicAdd(&h[k.z >> KSH], 1u);
        atomicAdd(&h[k.w >> KSH], 1u);
    }
    __syncthreads();
    u32* gh = ghist + (size_t)c * NBINS;
    for (int i = threadIdx.x; i < NBINS; i += 256) {
        u32 v = h[i];
        if (v) atomicAdd(&gh[i], v);
    }
}

// ------- Stage 2b: per-class pivot bin (parallel scan, LDS-staged) -------
__global__ __launch_bounds__(256)
void pivot_kernel(const u32* __restrict__ ghist, u32* __restrict__ pivotP,
                  u32* __restrict__ cnt) {
    __shared__ u32 hist[NBINS];   // 32 KB
    __shared__ u32 csum[256];
    __shared__ u32 sP;
    const int c = blockIdx.x, tid = threadIdx.x;
    const u32* gh = ghist + (size_t)c * NBINS;
    for (int i = tid; i < NBINS; i += 256) hist[i] = gh[i];
    if (tid == 0) sP = 0;
    __syncthreads();
    u32 own = 0; const int hi = NBINS - 1 - 32 * tid;
    #pragma unroll 4
    for (int j = 0; j < 32; ++j) own += hist[hi - j];
    csum[tid] = own;
    __syncthreads();
    for (int off = 1; off < 256; off <<= 1) {
        u32 v = csum[tid];
        u32 a = (tid >= off) ? csum[tid - off] : 0u;
        __syncthreads();
        csum[tid] = v + a;
        __syncthreads();
    }
    const u32 incl = csum[tid], excl = incl - own;
    if (excl < (u32)KCAND && incl >= (u32)KCAND) {   // unique crossing chunk
        u32 cum = excl;
        for (int j = 0; j < 32; ++j) {
            u32 hv = hist[hi - j];
            if (cum + hv >= (u32)KCAND) { sP = (u32)(hi - j); break; }
            cum += hv;
        }
    }
    __syncthreads();
    if (tid == 0) { pivotP[c] = sP; cnt[c] = 0; }
}

// -------- Stage 2c: sliced collect of candidates >= pivot (vec4) --------
__global__ __launch_bounds__(256)
void collect_kernel(const u32* __restrict__ keysT, const u32* __restrict__ pivotP,
                    u32* __restrict__ cnt, u64* __restrict__ candbuf) {
    __shared__ u64 lbuf[CAND_CAP];   // 16 KB
    __shared__ int lcnt, gbase;
    const int c = blockIdx.x / NSLICE, s = blockIdx.x % NSLICE;
    if (threadIdx.x == 0) lcnt = 0;
    __syncthreads();
    const u32 P = pivotP[c];
    const int lo = s * VSLICE, hiEnd = min(VTOT, lo + VSLICE);
    const uint4* kv = (const uint4*)(keysT + (size_t)c * A_N);
    for (int i = lo + threadIdx.x; i < hiEnd; i += 256) {
        uint4 k = kv[i];
        u32 base = (u32)(4 * i);
        if ((k.x >> KSH) >= P) {
            int p = atomicAdd(&lcnt, 1);
            if (p < CAND_CAP) lbuf[p] = (((u64)(~k.x)) << 32) | base;
        }
        if ((k.y >> KSH) >= P) {
            int p = atomicAdd(&lcnt, 1);
            if (p < CAND_CAP) lbuf[p] = (((u64)(~k.y)) << 32) | (base + 1);
        }
        if ((k.z >> KSH) >= P) {
            int p = atomicAdd(&lcnt, 1);
            if (p < CAND_CAP) lbuf[p] = (((u64)(~k.z)) << 32) | (base + 2);
        }
        if ((k.w >> KSH) >= P) {
            int p = atomicAdd(&lcnt, 1);
            if (p < CAND_CAP) lbuf[p] = (((u64)(~k.w)) << 32) | (base + 3);
        }
    }
    __syncthreads();
    const int n = min(lcnt, CAND_CAP);
    if (threadIdx.x == 0) gbase = (int)atomicAdd(&cnt[c], (u32)n);
    __syncthreads();
    u64* cb = candbuf + (size_t)c * CAND_CAP;
    const int b = gbase;
    for (int i = threadIdx.x; i < n; i += 256) {
        int d = b + i;
        if (d < CAND_CAP) cb[d] = lbuf[i];
    }
}

// ------ Stage 3a: hybrid bitonic sort, emit sorted scores + SoA boxes ------
__global__ __launch_bounds__(1024)
void sort_kernel(const u64* __restrict__ candbuf, const u32* __restrict__ cnt,
                 const float4* __restrict__ boxes,
                 float* __restrict__ csc,
                 float* __restrict__ cbx, float* __restrict__ cby,
                 float* __restrict__ cbz, float* __restrict__ cbw) {
    __shared__ u64 sortbuf[2][CAND_CAP];   // 32 KB
    const int c = blockIdx.x, tid = threadIdx.x;
    const int l = tid & 63, w = tid >> 6;
    const int i0 = 128 * w + l, i1 = i0 + 64;

    const int n = min((int)cnt[c], CAND_CAP);
    const u64* cb = candbuf + (size_t)c * CAND_CAP;
    u64 v0 = (i0 < n) ? cb[i0] : ~0ULL;
    u64 v1 = (i1 < n) ? cb[i1] : ~0ULL;

    int p = 0;
    #pragma unroll
    for (u32 kk = 2; kk <= CAND_CAP; kk <<= 1) {
        #pragma unroll
        for (u32 j = kk >> 1; j > 0; j >>= 1) {
            if (j >= 128) {
                sortbuf[p][i0] = v0; sortbuf[p][i1] = v1;
                __syncthreads();
                u64 w0 = sortbuf[p][i0 ^ j], w1 = sortbuf[p][i1 ^ j];
                bool m0 = (((i0 & j) == 0) == ((i0 & kk) == 0));
                bool m1 = (((i1 & j) == 0) == ((i1 & kk) == 0));
                v0 = m0 ? (v0 < w0 ? v0 : w0) : (v0 > w0 ? v0 : w0);
                v1 = m1 ? (v1 < w1 ? v1 : w1) : (v1 > w1 ? v1 : w1);
                p ^= 1;
            } else if (j == 64) {
                bool up = ((i0 & kk) == 0);
                u64 mn = v0 < v1 ? v0 : v1, mx = v0 < v1 ? v1 : v0;
                v0 = up ? mn : mx; v1 = up ? mx : mn;
            } else {
                u64 w0 = shflx64(v0, (int)j), w1 = shflx64(v1, (int)j);
                bool m0 = (((i0 & j) == 0) == ((i0 & kk) == 0));
                bool m1 = (((i1 & j) == 0) == ((i1 & kk) == 0));
                v0 = m0 ? (v0 < w0 ? v0 : w0) : (v0 > w0 ? v0 : w0);
                v1 = m1 ? (v1 < w1 ? v1 : w1) : (v1 > w1 ? v1 : w1);
            }
        }
    }
    if (w < 4) {   // i0,i1 < 512
        u32 idx0 = (u32)v0, key0 = ~((u32)(v0 >> 32));
        u32 idx1 = (u32)v1, key1 = ~((u32)(v1 >> 32));
        float4 b0 = boxes[idx0], b1 = boxes[idx1];
        const int o0 = c * KCAND + i0, o1 = c * KCAND + i1;
        csc[o0] = unfkey(key0); csc[o1] = unfkey(key1);
        cbx[o0] = b0.x; cby[o0] = b0.y; cbz[o0] = b0.z; cbw[o0] = b0.w;
        cbx[o1] = b1.x; cby[o1] = b1.y; cbz[o1] = b1.z; cbw[o1] = b1.w;
    }
}

// ------ Stage 3b: IoU mask, 8 blocks/class, no atomics, direct uint2 writes ------
__global__ __launch_bounds__(512)
void mask_kernel(const float* __restrict__ cbx, const float* __restrict__ cby,
                 const float* __restrict__ cbz, const float* __restrict__ cbw,
                 u32* __restrict__ bmaskG) {
    __shared__ float sx[KCAND], sy[KCAND], sz[KCAND], sw[KCAND], sa[KCAND]; // 10 KB
    const int c = blockIdx.x >> 3, rb = blockIdx.x & 7, tid = threadIdx.x;
    const int base = c * KCAND;
    if (tid < KCAND) {
        float x = cbx[base + tid], y = cby[base + tid];
        float z = cbz[base + tid], w = cbw[base + tid];
        sx[tid] = x; sy[tid] = y; sz[tid] = z; sw[tid] = w;
        sa[tid] = (z - x) * (w - y);
    }
    __syncthreads();
    const int r = tid >> 3, q = tid & 7;       // 64 rows/block, 8 threads/row
    const int i = rb * 64 + r;
    const float bix = sx[i], biy = sy[i], biz = sz[i], biw = sw[i], ai = sa[i];
    const int j0 = q * 64;
    u32 w0 = 0, w1 = 0;
    #pragma unroll 4
    for (int jj = 0; jj < 32; ++jj) {
        int j = j0 + jj;
        float xx1 = fmaxf(bix, sx[j]), yy1 = fmaxf(biy, sy[j]);
        float xx2 = fminf(biz, sz[j]), yy2 = fminf(biw, sw[j]);
        float inter = fmaxf(xx2 - xx1, 0.0f) * fmaxf(yy2 - yy1, 0.0f);
        float uni = ai + sa[j] - inter + 1e-8f;
        if (j > i && inter > 0.5f * uni) w0 |= (1u << jj);
    }
    #pragma unroll 4
    for (int jj = 0; jj < 32; ++jj) {
        int j = j0 + 32 + jj;
        float xx1 = fmaxf(bix, sx[j]), yy1 = fmaxf(biy, sy[j]);
        float xx2 = fminf(biz, sz[j]), yy2 = fminf(biw, sw[j]);
        float inter = fmaxf(xx2 - xx1, 0.0f) * fmaxf(yy2 - yy1, 0.0f);
        float uni = ai + sa[j] - inter + 1e-8f;
        if (j > i && inter > 0.5f * uni) w1 |= (1u << jj);
    }
    uint2 v; v.x = w0; v.y = w1;
    *((uint2*)(bmaskG + ((size_t)(base + i) * 16 + 2 * q))) = v;
}

// ------ Stage 3c: greedy NMS scan (stage mask to LDS, readlane chain) ------
__global__ __launch_bounds__(256)
void scan_kernel(const u32* __restrict__ bmaskG, const float* __restrict__ csc,
                 float* __restrict__ kept) {
    __shared__ u32 smask[KCAND * 16];   // 32 KB
    __shared__ float ssc[KCAND];
    __shared__ u32 keepf[16];
    const int c = blockIdx.x, tid = threadIdx.x;
    const uint4* src = (const uint4*)(bmaskG + (size_t)c * KCAND * 16);
    uint4* dst = (uint4*)smask;
    for (int i = tid; i < KCAND * 4; i += 256) dst[i] = src[i];
    for (int i = tid; i < KCAND; i += 256) ssc[i] = csc[c * KCAND + i];
    if (tid < 16) keepf[tid] = 0;
    __syncthreads();

    if (tid < 64) {
        const int lw = tid & 15;
        u32 removed = 0, keepw = 0;
        u32 rA[8], rB[8]; float sA[8], sB[8];
        #pragma unroll
        for (int k = 0; k < 8; ++k) { rA[k] = smask[k * 16 + lw]; sA[k] = ssc[k]; }
        #pragma unroll 1
        for (int ch = 0; ch < 64; ch += 2) {
            const int tb1 = (ch + 1) * 8;
            #pragma unroll
            for (int k = 0; k < 8; ++k) { rB[k] = smask[(tb1 + k) * 16 + lw]; sB[k] = ssc[tb1 + k]; }
            {
                const int tb = ch * 8;
                #pragma unroll
                for (int k = 0; k < 8; ++k) {
                    const int t = tb + k;
                    u32 rw = (u32)__builtin_amdgcn_readlane((int)removed, t >> 5);
                    bool d = (sA[k] > THRESH) && (((rw >> (t & 31)) & 1u) == 0u);
                    removed |= d ? rA[k] : 0u;
                    keepw |= (d && (tid == (t >> 5))) ? (1u << (t & 31)) : 0u;
                }
            }
            const int tb2 = (ch + 2 < 64) ? (ch + 2) * 8 : 0;
            #pragma unroll
            for (int k = 0; k < 8; ++k) { rA[k] = smask[(tb2 + k) * 16 + lw]; sA[k] = ssc[tb2 + k]; }
            {
                #pragma unroll
                for (int k = 0; k < 8; ++k) {
                    const int t = tb1 + k;
                    u32 rw = (u32)__builtin_amdgcn_readlane((int)removed, t >> 5);
                    bool d = (sB[k] > THRESH) && (((rw >> (t & 31)) & 1u) == 0u);
                    removed |= d ? rB[k] : 0u;
                    keepw |= (d && (tid == (t >> 5))) ? (1u << (t & 31)) : 0u;
                }
            }
        }
        if (tid < 16) keepf[tid] = keepw;
    }
    __syncthreads();
    for (int i = tid; i < KCAND; i += 256) {
        bool k = (keepf[i >> 5] >> (i & 31)) & 1u;
        kept[c * KCAND + i] = k ? ssc[i] : -1.0f;
    }
}

// ------- Stage 4: global top-100 (parallel scan + sized sort) -------
__global__ __launch_bounds__(1024)
void final_kernel(const float* __restrict__ kept,
                  const float* __restrict__ cbx, const float* __restrict__ cby,
                  const float* __restrict__ cbz, const float* __restrict__ cbw,
                  float* __restrict__ out) {
    __shared__ u32 hist[NBINS];   // 32 KB
    __shared__ u32 csum[1024];
    __shared__ u64 buf[1024];     // 8 KB
    __shared__ u32 sP;
    __shared__ int sN;
    const int tid = threadIdx.x;
    const int TOT = C_N * KCAND;
    for (int i = tid; i < NBINS; i += 1024) hist[i] = 0;
    if (tid == 0) { sN = 0; sP = 0; }
    __syncthreads();
    for (int i = tid; i < TOT; i += 1024) {
        float s = kept[i];
        if (s > 0.0f) atomicAdd(&hist[fkey(s) >> KSH], 1u);
    }
    __syncthreads();
    u32 own = 0; const int hi = NBINS - 1 - 8 * tid;
    #pragma unroll
    for (int j = 0; j < 8; ++j) own += hist[hi - j];
    csum[tid] = own;
    __syncthreads();
    for (int off = 1; off < 1024; off <<= 1) {
        u32 v = csum[tid];
        u32 a = (tid >= off) ? csum[tid - off] : 0u;
        __syncthreads();
        csum[tid] = v + a;
        __syncthreads();
    }
    const u32 incl = csum[tid], excl = incl - own;
    if (excl < (u32)MAXDET && incl >= (u32)MAXDET) {
        u32 cum = excl;
        for (int j = 0; j < 8; ++j) {
            u32 h = hist[hi - j];
            if (cum + h >= (u32)MAXDET) { sP = (u32)(hi - j); break; }
            cum += h;
        }
    }
    __syncthreads();
    const u32 P = sP;
    for (int i = tid; i < TOT; i += 1024) {
        float s = kept[i];
        if (s > 0.0f && (fkey(s) >> KSH) >= P) {
            int p = atomicAdd(&sN, 1);
            if (p < 1024)
                buf[p] = (((u64)(~fkey(s))) << 32) | (u32)i;
        }
    }
    __syncthreads();
    const int n = min(sN, 1024);
    u32 m = 128; while ((int)m < n) m <<= 1;   // uniform across block
    for (int i = tid; i < (int)m; i += 1024) if (i >= n) buf[i] = ~0ULL;
    __syncthreads();
    for (u32 kk = 2; kk <= m; kk <<= 1) {
        for (u32 j = kk >> 1; j > 0; j >>= 1) {
            u32 i = (u32)tid;
            if (i < m) {
                u32 ixj = i ^ j;
                if (ixj > i) {
                    u64 x = buf[i], y = buf[ixj];
                    bool up = ((i & kk) == 0);
                    if (up ? (x > y) : (x < y)) { buf[i] = y; buf[ixj] = x; }
                }
            }
            __syncthreads();
        }
    }
    if (tid < MAXDET) {
        float row1 = 0, row2 = 0, row3 = 0, row4 = 0, row5 = 0, row6 = 0;
        if (tid < n) {
            u64 comp = buf[tid];
            u32 flat = (u32)comp;
            u32 key = ~((u32)(comp >> 32));
            float s = unfkey(key);
            if (s > 0.0f) {
                row1 = cbx[flat]; row2 = cby[flat];
                row3 = cbz[flat]; row4 = cbw[flat];
                row5 = s; row6 = (float)(flat >> 9);   // flat / 512 = class label
            }
        }
        float* o = out + tid * 7;
        o[0] = 0.0f; o[1] = row1; o[2] = row2; o[3] = row3;
        o[4] = row4; o[5] = row5; o[6] = row6;
    }
}

extern "C" void kernel_launch(void* const* d_in, const int* in_sizes, int n_in,
                              void* d_out, int out_size, void* d_ws, size_t ws_size,
                              hipStream_t stream) {
    const float* reg     = (const float*)d_in[1];
    const float* cls     = (const float*)d_in[2];
    const float* anchors = (const float*)d_in[3];
    float* out = (float*)d_out;

    char* ws = (char*)d_ws;
    size_t off = 0;
    auto alloc = [&](size_t bytes) -> void* {
        void* p = ws + off;
        off = (off + bytes + 255) & ~(size_t)255;
        return p;
    };
    u32*    keysT   = (u32*)   alloc((size_t)C_N * A_N * sizeof(u32));        // 39.8 MB
    float4* boxes   = (float4*)alloc((size_t)A_N * sizeof(float4));           // 1.77 MB
    u32*    ghist   = (u32*)   alloc((size_t)C_N * NBINS * sizeof(u32));      // 2.95 MB
    u32*    bmaskG  = ghist;   // alias: ghist dead after pivot, mask written after
    u32*    pivotP  = (u32*)   alloc((size_t)C_N * sizeof(u32));
    u32*    cnt     = (u32*)   alloc((size_t)C_N * sizeof(u32));
    u64*    candbuf = (u64*)   alloc((size_t)C_N * CAND_CAP * sizeof(u64));   // 1.47 MB
    float*  csc     = (float*) alloc((size_t)C_N * KCAND * sizeof(float));
    float*  cbx     = (float*) alloc((size_t)C_N * KCAND * sizeof(float));
    float*  cby     = (float*) alloc((size_t)C_N * KCAND * sizeof(float));
    float*  cbz     = (float*) alloc((size_t)C_N * KCAND * sizeof(float));
    float*  cbw     = (float*) alloc((size_t)C_N * KCAND * sizeof(float));
    float*  kept    = (float*) alloc((size_t)C_N * KCAND * sizeof(float));
    (void)ws_size;

    hipMemsetAsync(ghist, 0, (size_t)C_N * NBINS * sizeof(u32), stream);
    prep_kernel<<<T_BLKS + D_BLKS, 256, 0, stream>>>(anchors, reg, cls, boxes, keysT);
    hist_kernel<<<C_N * NSLICE, 256, 0, stream>>>(keysT, ghist);
    pivot_kernel<<<C_N, 256, 0, stream>>>(ghist, pivotP, cnt);
    collect_kernel<<<C_N * NSLICE, 256, 0, stream>>>(keysT, pivotP, cnt, candbuf);
    sort_kernel<<<C_N, 1024, 0, stream>>>(candbuf, cnt, boxes, csc, cbx, cby, cbz, cbw);
    mask_kernel<<<C_N * 8, 512, 0, stream>>>(cbx, cby, cbz, cbw, bmaskG);
    scan_kernel<<<C_N, 256, 0, stream>>>(bmaskG, csc, kept);
    final_kernel<<<1, 1024, 0, stream>>>(kept, cbx, cby, cbz, cbw, out);
}

// Round 7
// 244.970 us; speedup vs baseline: 1.1221x; 1.1221x over previous
//
#include <hip/hip_runtime.h>
#include <math.h>

// EfficientDet post-processing, device pipeline v7 (5 launches).
// prep(decode+transpose+zero) -> sliced hist -> collect(inline pivot) ->
// snms(sort+mask+scan+compact) -> final(single-wave 90-way merge).

#define A_N   110484
#define C_N   90
#define KCAND 512
#define NBINS 8192        // 13-bit histogram bins (key >> 19)
#define KSH   19
#define MAXDET 100
#define IMG_F 768.0f
#define THRESH 0.05f
#define NSLICE 8
#define VTOT   (A_N / 4)                          // 27621 (A_N divisible by 4)
#define VSLICE ((VTOT + NSLICE - 1) / NSLICE)     // 3453
#define CAND_CAP 2048
#define KEEP_CAP 100
#define T_BLKS ((A_N + 63) / 64)     // 1727 transpose blocks
#define D_BLKS ((A_N + 255) / 256)   // 432 decode blocks
#define Z_BLKS 64                    // zero-fill blocks for ghist/cnt

typedef unsigned int u32;
typedef unsigned long long u64;

__device__ __forceinline__ u32 fkey(float f) {
    u32 u = __float_as_uint(f);
    return (u & 0x80000000u) ? ~u : (u | 0x80000000u);
}
__device__ __forceinline__ float unfkey(u32 k) {
    u32 u = (k & 0x80000000u) ? (k ^ 0x80000000u) : ~k;
    return __uint_as_float(u);
}
__device__ __forceinline__ u64 shflx64(u64 v, int m) {
    u32 lo = (u32)__shfl_xor((int)(u32)v, m, 64);
    u32 hi = (u32)__shfl_xor((int)(v >> 32), m, 64);
    return ((u64)hi << 32) | lo;
}

// ------- Stage 1: decode + transpose + zero(ghist,cnt), one launch -------
__global__ __launch_bounds__(256)
void prep_kernel(const float* __restrict__ anchors,
                 const float* __restrict__ reg,
                 const float* __restrict__ cls,
                 float4* __restrict__ boxes,
                 u32* __restrict__ keysT,
                 u32* __restrict__ ghist,
                 u32* __restrict__ cnt) {
    __shared__ u32 tile[64 * 91];   // 23.3 KB, stride 91 (odd) = conflict-free
    if (blockIdx.x >= T_BLKS + D_BLKS) {   // zero blocks
        const int z = blockIdx.x - (T_BLKS + D_BLKS);
        uint4* g4 = (uint4*)ghist;
        const int tot4 = C_N * NBINS / 4;
        uint4 zero4; zero4.x = zero4.y = zero4.z = zero4.w = 0u;
        for (int i = z * 256 + threadIdx.x; i < tot4; i += Z_BLKS * 256)
            g4[i] = zero4;
        if (z == 0 && threadIdx.x < C_N) cnt[threadIdx.x] = 0u;
        return;
    }
    if (blockIdx.x >= T_BLKS) {   // decode blocks
        int a = (blockIdx.x - T_BLKS) * 256 + threadIdx.x;
        if (a >= A_N) return;
        float4 an = ((const float4*)anchors)[a];
        float4 dl = ((const float4*)reg)[a];
        float wa = an.z - an.x, ha = an.w - an.y;
        float cx = an.x + 0.5f * wa + dl.x * wa;
        float cy = an.y + 0.5f * ha + dl.y * ha;
        float w = expf(dl.z) * wa;
        float h = expf(dl.w) * ha;
        float4 o;
        o.x = fminf(fmaxf(cx - 0.5f * w, 0.0f), IMG_F);
        o.y = fminf(fmaxf(cy - 0.5f * h, 0.0f), IMG_F);
        o.z = fminf(fmaxf(cx + 0.5f * w, 0.0f), IMG_F);
        o.w = fminf(fmaxf(cy + 0.5f * h, 0.0f), IMG_F);
        boxes[a] = o;
        return;
    }
    // transpose blocks
    int a0 = blockIdx.x * 64;
    int lim = min(64, A_N - a0);
    int n = lim * C_N;
    const float* src = cls + (size_t)a0 * C_N;
    for (int i = threadIdx.x; i < n; i += 256) {
        float x = src[i];
        float s = 1.0f / (1.0f + expf(-x));
        u32 aa = (u32)i / C_N, c = (u32)i % C_N;
        tile[aa * 91 + c] = fkey(s);
    }
    __syncthreads();
    for (int j = threadIdx.x; j < C_N * 64; j += 256) {
        int c = j >> 6, aa = j & 63;
        if (aa < lim)
            keysT[(size_t)c * A_N + a0 + aa] = tile[aa * 91 + c];
    }
}

// ---------------- Stage 2: sliced per-class histogram (vec4) ----------------
__global__ __launch_bounds__(256)
void hist_kernel(const u32* __restrict__ keysT, u32* __restrict__ ghist) {
    __shared__ u32 h[NBINS];   // 32 KB
    const int c = blockIdx.x / NSLICE, s = blockIdx.x % NSLICE;
    for (int i = threadIdx.x; i < NBINS; i += 256) h[i] = 0;
    __syncthreads();
    const int lo = s * VSLICE, hiEnd = min(VTOT, lo + VSLICE);
    const uint4* kv = (const uint4*)(keysT + (size_t)c * A_N);
    for (int i = lo + threadIdx.x; i < hiEnd; i += 256) {
        uint4 k = kv[i];
        atomicAdd(&h[k.x >> KSH], 1u);
        atomicAdd(&h[k.y >> KSH], 1u);
        atomicAdd(&h[k.z >> KSH], 1u);
        atomicAdd(&h[k.w >> KSH], 1u);
    }
    __syncthreads();
    u32* gh = ghist + (size_t)c * NBINS;
    for (int i = threadIdx.x; i < NBINS; i += 256) {
        u32 v = h[i];
        if (v) atomicAdd(&gh[i], v);
    }
}

// ------ Stage 3: collect with inline pivot (redundant per block, L2-hot) ------
__global__ __launch_bounds__(256)
void collect_kernel(const u32* __restrict__ keysT, const u32* __restrict__ ghist,
                    u32* __restrict__ cnt, u64* __restrict__ candbuf) {
    __shared__ u32 hist[NBINS];      // 32 KB
    __shared__ u32 csum[256];
    __shared__ u64 lbuf[CAND_CAP];   // 16 KB
    __shared__ u32 sPv;
    __shared__ int lcnt, gbase;
    const int c = blockIdx.x / NSLICE, s = blockIdx.x % NSLICE;
    const int tid = threadIdx.x;
    const u32* gh = ghist + (size_t)c * NBINS;
    for (int i = tid; i < NBINS; i += 256) hist[i] = gh[i];
    if (tid == 0) { sPv = 0; lcnt = 0; }
    __syncthreads();
    // pivot: descending chunk sums + Hillis-Steele scan + local walk
    u32 own = 0; const int hi = NBINS - 1 - 32 * tid;
    #pragma unroll 4
    for (int j = 0; j < 32; ++j) own += hist[hi - j];
    csum[tid] = own;
    __syncthreads();
    for (int off = 1; off < 256; off <<= 1) {
        u32 v = csum[tid];
        u32 a = (tid >= off) ? csum[tid - off] : 0u;
        __syncthreads();
        csum[tid] = v + a;
        __syncthreads();
    }
    const u32 incl = csum[tid], excl = incl - own;
    if (excl < (u32)KCAND && incl >= (u32)KCAND) {
        u32 cum = excl;
        for (int j = 0; j < 32; ++j) {
            u32 hv = hist[hi - j];
            if (cum + hv >= (u32)KCAND) { sPv = (u32)(hi - j); break; }
            cum += hv;
        }
    }
    __syncthreads();
    const u32 P = sPv;
    const int lo = s * VSLICE, hiEnd = min(VTOT, lo + VSLICE);
    const uint4* kv = (const uint4*)(keysT + (size_t)c * A_N);
    for (int i = lo + tid; i < hiEnd; i += 256) {
        uint4 k = kv[i];
        u32 base = (u32)(4 * i);
        if ((k.x >> KSH) >= P) {
            int p = atomicAdd(&lcnt, 1);
            if (p < CAND_CAP) lbuf[p] = (((u64)(~k.x)) << 32) | base;
        }
        if ((k.y >> KSH) >= P) {
            int p = atomicAdd(&lcnt, 1);
            if (p < CAND_CAP) lbuf[p] = (((u64)(~k.y)) << 32) | (base + 1);
        }
        if ((k.z >> KSH) >= P) {
            int p = atomicAdd(&lcnt, 1);
            if (p < CAND_CAP) lbuf[p] = (((u64)(~k.z)) << 32) | (base + 2);
        }
        if ((k.w >> KSH) >= P) {
            int p = atomicAdd(&lcnt, 1);
            if (p < CAND_CAP) lbuf[p] = (((u64)(~k.w)) << 32) | (base + 3);
        }
    }
    __syncthreads();
    const int n = min(lcnt, CAND_CAP);
    if (tid == 0) gbase = (int)atomicAdd(&cnt[c], (u32)n);
    __syncthreads();
    u64* cb = candbuf + (size_t)c * CAND_CAP;
    const int b = gbase;
    for (int i = tid; i < n; i += 256) {
        int d = b + i;
        if (d < CAND_CAP) cb[d] = lbuf[i];
    }
}

// ---- Stage 4: fused sort + IoU mask + greedy scan + compact kept lists ----
__global__ __launch_bounds__(1024)
void snms_kernel(const u64* __restrict__ candbuf, const u32* __restrict__ cnt,
                 const float4* __restrict__ boxes,
                 u32* __restrict__ keptbuf, u32* __restrict__ cnt2) {
    __shared__ u64 sortbuf[2][CAND_CAP];   // 32 KB, reused as bmask after sort
    __shared__ float bxx[KCAND], byy[KCAND], bzz[KCAND], bww[KCAND];
    __shared__ float ar[KCAND], sc[KCAND];
    __shared__ u32 keepf[16];
    __shared__ u32 wbase[17];
    u32* bmask = (u32*)&sortbuf[0][0];     // 512 rows x 16 words = 32 KB
    const int c = blockIdx.x, tid = threadIdx.x;
    const int l = tid & 63, w = tid >> 6;
    const int i0 = 128 * w + l, i1 = i0 + 64;

    // --- hybrid bitonic sort of 2048 (asc composite = score desc, idx asc) ---
    const int n = min((int)cnt[c], CAND_CAP);
    const u64* cb = candbuf + (size_t)c * CAND_CAP;
    u64 v0 = (i0 < n) ? cb[i0] : ~0ULL;
    u64 v1 = (i1 < n) ? cb[i1] : ~0ULL;
    int p = 0;
    #pragma unroll
    for (u32 kk = 2; kk <= CAND_CAP; kk <<= 1) {
        #pragma unroll
        for (u32 j = kk >> 1; j > 0; j >>= 1) {
            if (j >= 128) {
                sortbuf[p][i0] = v0; sortbuf[p][i1] = v1;
                __syncthreads();
                u64 w0 = sortbuf[p][i0 ^ j], w1 = sortbuf[p][i1 ^ j];
                bool m0 = (((i0 & j) == 0) == ((i0 & kk) == 0));
                bool m1 = (((i1 & j) == 0) == ((i1 & kk) == 0));
                v0 = m0 ? (v0 < w0 ? v0 : w0) : (v0 > w0 ? v0 : w0);
                v1 = m1 ? (v1 < w1 ? v1 : w1) : (v1 > w1 ? v1 : w1);
                p ^= 1;
            } else if (j == 64) {
                bool up = ((i0 & kk) == 0);
                u64 mn = v0 < v1 ? v0 : v1, mx = v0 < v1 ? v1 : v0;
                v0 = up ? mn : mx; v1 = up ? mx : mn;
            } else {
                u64 w0 = shflx64(v0, (int)j), w1 = shflx64(v1, (int)j);
                bool m0 = (((i0 & j) == 0) == ((i0 & kk) == 0));
                bool m1 = (((i1 & j) == 0) == ((i1 & kk) == 0));
                v0 = m0 ? (v0 < w0 ? v0 : w0) : (v0 > w0 ? v0 : w0);
                v1 = m1 ? (v1 < w1 ? v1 : w1) : (v1 > w1 ? v1 : w1);
            }
        }
    }
    __syncthreads();   // sort done in registers; sortbuf free for bmask

    // --- top-512 -> SoA; zero mask ---
    if (w < 4) {
        u32 idx0 = (u32)v0, key0 = ~((u32)(v0 >> 32));
        u32 idx1 = (u32)v1, key1 = ~((u32)(v1 >> 32));
        sc[i0] = unfkey(key0); sc[i1] = unfkey(key1);
        float4 b0 = boxes[idx0], b1 = boxes[idx1];
        bxx[i0] = b0.x; byy[i0] = b0.y; bzz[i0] = b0.z; bww[i0] = b0.w;
        bxx[i1] = b1.x; byy[i1] = b1.y; bzz[i1] = b1.z; bww[i1] = b1.w;
        ar[i0] = (b0.z - b0.x) * (b0.w - b0.y);
        ar[i1] = (b1.z - b1.x) * (b1.w - b1.y);
    }
    for (int i = tid; i < KCAND * 16; i += 1024) bmask[i] = 0;
    if (tid < 16) keepf[tid] = 0;
    __syncthreads();

    // --- upper-triangular IoU mask, 2 threads per row ---
    {
        const int i = tid & (KCAND - 1);
        const int half = tid >> 9;
        const int count = (KCAND - 1) - i;
        const int j0 = i + 1 + (half ? (count >> 1) : 0);
        const int j1 = half ? KCAND : (i + 1 + (count >> 1));
        const float bix = bxx[i], biy = byy[i], biz = bzz[i], biw = bww[i];
        const float ai = ar[i];
        u32 m[16];
        #pragma unroll
        for (int q = 0; q < 16; ++q) m[q] = 0;
        for (int j = j0; j < j1; ++j) {
            float xx1 = fmaxf(bix, bxx[j]), yy1 = fmaxf(biy, byy[j]);
            float xx2 = fminf(biz, bzz[j]), yy2 = fminf(biw, bww[j]);
            float inter = fmaxf(xx2 - xx1, 0.0f) * fmaxf(yy2 - yy1, 0.0f);
            float uni = ai + ar[j] - inter + 1e-8f;
            if (inter > 0.5f * uni) m[j >> 5] |= (1u << (j & 31));
        }
        #pragma unroll
        for (int q = 0; q < 16; ++q)
            if (m[q]) atomicOr(&bmask[i * 16 + q], m[q]);
    }
    __syncthreads();

    // --- greedy scan, wave 0; register-pipelined rows + readlane chain ---
    if (tid < 64) {
        const int lw = tid & 15;
        u32 removed = 0, keepw = 0;
        u32 rA[8], rB[8]; float sA[8], sB[8];
        #pragma unroll
        for (int k = 0; k < 8; ++k) { rA[k] = bmask[k * 16 + lw]; sA[k] = sc[k]; }
        #pragma unroll 1
        for (int ch = 0; ch < 64; ch += 2) {
            const int tb1 = (ch + 1) * 8;
            #pragma unroll
            for (int k = 0; k < 8; ++k) { rB[k] = bmask[(tb1 + k) * 16 + lw]; sB[k] = sc[tb1 + k]; }
            {
                const int tb = ch * 8;
                #pragma unroll
                for (int k = 0; k < 8; ++k) {
                    const int t = tb + k;
                    u32 rw = (u32)__builtin_amdgcn_readlane((int)removed, t >> 5);
                    bool d = (sA[k] > THRESH) && (((rw >> (t & 31)) & 1u) == 0u);
                    removed |= d ? rA[k] : 0u;
                    keepw |= (d && (tid == (t >> 5))) ? (1u << (t & 31)) : 0u;
                }
            }
            const int tb2 = (ch + 2 < 64) ? (ch + 2) * 8 : 0;
            #pragma unroll
            for (int k = 0; k < 8; ++k) { rA[k] = bmask[(tb2 + k) * 16 + lw]; sA[k] = sc[tb2 + k]; }
            {
                #pragma unroll
                for (int k = 0; k < 8; ++k) {
                    const int t = tb1 + k;
                    u32 rw = (u32)__builtin_amdgcn_readlane((int)removed, t >> 5);
                    bool d = (sB[k] > THRESH) && (((rw >> (t & 31)) & 1u) == 0u);
                    removed |= d ? rB[k] : 0u;
                    keepw |= (d && (tid == (t >> 5))) ? (1u << (t & 31)) : 0u;
                }
            }
        }
        if (tid < 16) keepf[tid] = keepw;
    }
    __syncthreads();

    // --- compact kept (sorted order) to keptbuf, cap 100/class ---
    if (tid == 0) {
        u32 t = 0;
        for (int q = 0; q < 16; ++q) { wbase[q] = t; t += __popc(keepf[q]); }
        wbase[16] = t;
        cnt2[c] = (t < (u32)KEEP_CAP) ? t : (u32)KEEP_CAP;
    }
    __syncthreads();
    if (tid < KCAND) {
        u32 word = keepf[tid >> 5];
        u32 bit = (u32)tid & 31u;
        if ((word >> bit) & 1u) {
            u32 rank = wbase[tid >> 5] + __popc(word & ((1u << bit) - 1u));
            if (rank < (u32)KEEP_CAP) {
                float s = sc[tid];
                uint4 a, b;
                a.x = ~fkey(s);
                a.y = (u32)(c * KCAND + tid);
                a.z = __float_as_uint(bxx[tid]);
                a.w = __float_as_uint(byy[tid]);
                b.x = __float_as_uint(bzz[tid]);
                b.y = __float_as_uint(bww[tid]);
                b.z = __float_as_uint(s);
                b.w = 0u;
                uint4* e = (uint4*)(keptbuf + ((size_t)c * KEEP_CAP + rank) * 8);
                e[0] = a; e[1] = b;
            }
        }
    }
}

// ------- Stage 5: single-wave 90-way sorted-list merge -> top-100 rows -------
__global__ __launch_bounds__(64)
void final_kernel(const u32* __restrict__ keptbuf, const u32* __restrict__ cnt2,
                  float* __restrict__ out) {
    const int l = threadIdx.x;
    for (int i = l; i < MAXDET * 7; i += 64) out[i] = 0.0f;

    // lane l owns class l (always, l<64<90) and class l+64 (if <90)
    const int cA = l, cB = l + 64;
    int nA = min((int)cnt2[cA], KEEP_CAP);
    int nB = (cB < C_N) ? min((int)cnt2[cB], KEEP_CAP) : 0;

    u64 curcA = ~0ULL, nxtcA = ~0ULL, curcB = ~0ULL, nxtcB = ~0ULL;
    float4 curbA, nxtbA, curbB, nxtbB;
    float cursA = 0, nxtsA = 0, cursB = 0, nxtsB = 0;
    int ptrA = 0, ptrB = 0;

    #define LOADE(c, p, comp, bx, s) { \
        const uint4* e_ = (const uint4*)(keptbuf + ((size_t)(c) * KEEP_CAP + (p)) * 8); \
        uint4 a_ = e_[0], b_ = e_[1]; \
        comp = ((u64)a_.x << 32) | a_.y; \
        bx.x = __uint_as_float(a_.z); bx.y = __uint_as_float(a_.w); \
        bx.z = __uint_as_float(b_.x); bx.w = __uint_as_float(b_.y); \
        s = __uint_as_float(b_.z); }

    if (nA > 0) LOADE(cA, 0, curcA, curbA, cursA);
    if (nA > 1) LOADE(cA, 1, nxtcA, nxtbA, nxtsA);
    if (nB > 0) LOADE(cB, 0, curcB, curbB, cursB);
    if (nB > 1) LOADE(cB, 1, nxtcB, nxtbB, nxtsB);

    for (int r = 0; r < MAXDET; ++r) {
        u64 g = curcA < curcB ? curcA : curcB;
        #pragma unroll
        for (int st = 1; st < 64; st <<= 1) {
            u64 o = shflx64(g, st);
            g = o < g ? o : g;
        }
        if (g == ~0ULL) break;   // uniform: all streams exhausted
        if (curcA == g) {
            float* o = out + r * 7;
            o[0] = 0.0f; o[1] = curbA.x; o[2] = curbA.y; o[3] = curbA.z;
            o[4] = curbA.w; o[5] = cursA; o[6] = (float)(((u32)g) >> 9);
            curcA = nxtcA; curbA = nxtbA; cursA = nxtsA;
            ++ptrA;
            if (ptrA + 1 < nA) { LOADE(cA, ptrA + 1, nxtcA, nxtbA, nxtsA); }
            else nxtcA = ~0ULL;
        } else if (curcB == g) {
            float* o = out + r * 7;
            o[0] = 0.0f; o[1] = curbB.x; o[2] = curbB.y; o[3] = curbB.z;
            o[4] = curbB.w; o[5] = cursB; o[6] = (float)(((u32)g) >> 9);
            curcB = nxtcB; curbB = nxtbB; cursB = nxtsB;
            ++ptrB;
            if (ptrB + 1 < nB) { LOADE(cB, ptrB + 1, nxtcB, nxtbB, nxtsB); }
            else nxtcB = ~0ULL;
        }
    }
    #undef LOADE
}

extern "C" void kernel_launch(void* const* d_in, const int* in_sizes, int n_in,
                              void* d_out, int out_size, void* d_ws, size_t ws_size,
                              hipStream_t stream) {
    const float* reg     = (const float*)d_in[1];
    const float* cls     = (const float*)d_in[2];
    const float* anchors = (const float*)d_in[3];
    float* out = (float*)d_out;

    char* ws = (char*)d_ws;
    size_t off = 0;
    auto alloc = [&](size_t bytes) -> void* {
        void* p = ws + off;
        off = (off + bytes + 255) & ~(size_t)255;
        return p;
    };
    u32*    keysT   = (u32*)   alloc((size_t)C_N * A_N * sizeof(u32));        // 39.8 MB
    float4* boxes   = (float4*)alloc((size_t)A_N * sizeof(float4));           // 1.77 MB
    u32*    ghist   = (u32*)   alloc((size_t)C_N * NBINS * sizeof(u32));      // 2.95 MB
    u32*    cnt     = (u32*)   alloc((size_t)C_N * sizeof(u32));
    u32*    cnt2    = (u32*)   alloc((size_t)C_N * sizeof(u32));
    u64*    candbuf = (u64*)   alloc((size_t)C_N * CAND_CAP * sizeof(u64));   // 1.47 MB
    u32*    keptbuf = (u32*)   alloc((size_t)C_N * KEEP_CAP * 8 * sizeof(u32)); // 288 KB
    (void)ws_size;

    prep_kernel<<<T_BLKS + D_BLKS + Z_BLKS, 256, 0, stream>>>(
        anchors, reg, cls, boxes, keysT, ghist, cnt);
    hist_kernel<<<C_N * NSLICE, 256, 0, stream>>>(keysT, ghist);
    collect_kernel<<<C_N * NSLICE, 256, 0, stream>>>(keysT, ghist, cnt, candbuf);
    snms_kernel<<<C_N, 1024, 0, stream>>>(candbuf, cnt, boxes, keptbuf, cnt2);
    final_kernel<<<1, 64, 0, stream>>>(keptbuf, cnt2, out);
}